// Round 2
// baseline (710.185 us; speedup 1.0000x reference)
//
#include <hip/hip_runtime.h>
#include <hip/hip_bf16.h>
#include <math.h>

typedef __bf16 bf16_t;
typedef __bf16 bf16x8 __attribute__((ext_vector_type(8)));
typedef float f32x4 __attribute__((ext_vector_type(4)));

#define T_DIM 2048
#define C_DIM 2048
#define NH 16
#define HS 128
#define NLQ 1536
#define NLKV 512
#define DHR 64
#define QKD 192  // HS + DHR

// ---------------------------------------------------------------- dtype detect
// If inputs are f32 and we read them as bf16, the low-half (even index) words
// have random exponent bits -> huge/NaN values. True bf16 inputs are ~N(0,1).
__global__ void detect_k(const bf16_t* __restrict__ x, int* __restrict__ flag) {
  int bad = 0;
  for (int i = threadIdx.x; i < 256; i += 64) {
    float v = (float)x[i];
    if (!(fabsf(v) < 1.0e6f)) bad = 1;  // catches NaN too
  }
  unsigned long long m = __ballot(bad);
  if (threadIdx.x == 0) *flag = (m != 0ull) ? 1 : 0;
}

// normalize any input to bf16
__global__ void convert_k(const void* __restrict__ in, bf16_t* __restrict__ out,
                          int n, const int* __restrict__ flag) {
  int i = blockIdx.x * blockDim.x + threadIdx.x;
  if (i >= n) return;
  if (*flag) out[i] = (bf16_t)((const float*)in)[i];
  else       out[i] = ((const bf16_t*)in)[i];
}

// ---------------------------------------------------------------- transpose
__global__ void transpose_k(const bf16_t* __restrict__ in, bf16_t* __restrict__ out,
                            int R, int C) {
  __shared__ bf16_t tile[32][33];
  int bx = blockIdx.x * 32, by = blockIdx.y * 32;
  int tx = threadIdx.x, ty = threadIdx.y;
  for (int i = ty; i < 32; i += 8) {
    int r = by + i, c = bx + tx;
    if (r < R && c < C) tile[i][tx] = in[(size_t)r * C + c];
  }
  __syncthreads();
  for (int i = ty; i < 32; i += 8) {
    int r = bx + i, c = by + tx;  // out[r][c] = in[c][r]
    if (r < C && c < R) out[(size_t)r * R + c] = tile[tx][i];
  }
}

// ---------------------------------------------------------------- GEMM  C = A @ B^T
#define BM 128
#define BN 128
#define BK 32
#define APITCH 40

__global__ __launch_bounds__(256) void gemm_nt(const bf16_t* __restrict__ A,
                                               const bf16_t* __restrict__ B,
                                               bf16_t* __restrict__ Cm,
                                               int M, int N, int K,
                                               int lda, int ldb, int ldc) {
  __shared__ bf16_t As[BM * APITCH];
  __shared__ bf16_t Bs[BN * APITCH];
  const int tid = threadIdx.x;
  const int lane = tid & 63;
  const int wave = tid >> 6;
  const int l16 = lane & 15, quad = lane >> 4;
  const int bm = blockIdx.x * BM, bn = blockIdx.y * BN;
  const int wm = (wave >> 1) * 64, wn = (wave & 1) * 64;
  f32x4 acc[4][4] = {};

  for (int k0 = 0; k0 < K; k0 += BK) {
    __syncthreads();
#pragma unroll
    for (int r = 0; r < 2; ++r) {
      int idx = r * 256 + tid;
      int row = idx >> 2;
      int col = (idx & 3) * 8;
      int ar = bm + row; if (ar > M - 1) ar = M - 1;
      bf16x8 va = *(const bf16x8*)(A + (size_t)ar * lda + k0 + col);
      *(bf16x8*)(As + row * APITCH + col) = va;
      int br = bn + row; if (br > N - 1) br = N - 1;
      bf16x8 vb = *(const bf16x8*)(B + (size_t)br * ldb + k0 + col);
      *(bf16x8*)(Bs + row * APITCH + col) = vb;
    }
    __syncthreads();
    bf16x8 af[4], bfr[4];
#pragma unroll
    for (int i = 0; i < 4; ++i)
      af[i] = *(const bf16x8*)(As + (wm + i * 16 + l16) * APITCH + quad * 8);
#pragma unroll
    for (int j = 0; j < 4; ++j)
      bfr[j] = *(const bf16x8*)(Bs + (wn + j * 16 + l16) * APITCH + quad * 8);
#pragma unroll
    for (int i = 0; i < 4; ++i)
#pragma unroll
      for (int j = 0; j < 4; ++j)
        acc[i][j] = __builtin_amdgcn_mfma_f32_16x16x32_bf16(af[i], bfr[j], acc[i][j], 0, 0, 0);
  }
#pragma unroll
  for (int i = 0; i < 4; ++i)
#pragma unroll
    for (int j = 0; j < 4; ++j)
#pragma unroll
      for (int r = 0; r < 4; ++r) {
        int gm = bm + wm + i * 16 + quad * 4 + r;
        int gn = bn + wn + j * 16 + l16;
        if (gm < M && gn < N) Cm[(size_t)gm * ldc + gn] = (bf16_t)acc[i][j][r];
      }
}

// ---------------------------------------------------------------- pack + rope
__global__ void pack_q_k(const bf16_t* __restrict__ qup, const bf16_t* __restrict__ qr,
                         const bf16_t* __restrict__ fc, const bf16_t* __restrict__ fs,
                         bf16_t* __restrict__ Qp) {
  int idx = blockIdx.x * blockDim.x + threadIdx.x;
  if (idx >= NH * T_DIM * 96) return;
  int j = idx % 96;
  int t = (idx / 96) % T_DIM;
  int h = idx / (96 * T_DIM);
  const float scale = 0.07216878364870323f;  // 1/sqrt(HS+DHR)
  bf16_t* out = Qp + ((size_t)h * T_DIM + t) * QKD;
  if (j < 64) {
    float a = (float)qup[(size_t)t * C_DIM + h * HS + 2 * j];
    float b = (float)qup[(size_t)t * C_DIM + h * HS + 2 * j + 1];
    out[2 * j] = (bf16_t)(a * scale);
    out[2 * j + 1] = (bf16_t)(b * scale);
  } else {
    int i = j - 64;
    float re = (float)qr[(size_t)t * (NH * DHR) + h * DHR + 2 * i];
    float im = (float)qr[(size_t)t * (NH * DHR) + h * DHR + 2 * i + 1];
    float c = (float)fc[t * 32 + i], s = (float)fs[t * 32 + i];
    out[HS + 2 * i] = (bf16_t)((re * c - im * s) * scale);
    out[HS + 2 * i + 1] = (bf16_t)((re * s + im * c) * scale);
  }
}

__global__ void pack_k_k(const bf16_t* __restrict__ khead, const bf16_t* __restrict__ kr,
                         const bf16_t* __restrict__ fc, const bf16_t* __restrict__ fs,
                         bf16_t* __restrict__ Kp) {
  int idx = blockIdx.x * blockDim.x + threadIdx.x;
  if (idx >= NH * T_DIM * 96) return;
  int j = idx % 96;
  int t = (idx / 96) % T_DIM;
  int h = idx / (96 * T_DIM);
  bf16_t* out = Kp + ((size_t)h * T_DIM + t) * QKD;
  if (j < 64) {
    out[2 * j] = khead[(size_t)t * C_DIM + h * HS + 2 * j];
    out[2 * j + 1] = khead[(size_t)t * C_DIM + h * HS + 2 * j + 1];
  } else {
    int i = j - 64;
    float re = (float)kr[(size_t)t * DHR + 2 * i];
    float im = (float)kr[(size_t)t * DHR + 2 * i + 1];
    float c = (float)fc[t * 32 + i], s = (float)fs[t * 32 + i];
    out[HS + 2 * i] = (bf16_t)(re * c - im * s);
    out[HS + 2 * i + 1] = (bf16_t)(re * s + im * c);
  }
}

// ---------------------------------------------------------------- flash attention
#define FBM 64
#define FBN 64
#define KPITCH 200
#define VPITCH 72
#define PPITCH 72

__global__ __launch_bounds__(256) void flash_k(const bf16_t* __restrict__ Qp,
                                               const bf16_t* __restrict__ Kp,
                                               const bf16_t* __restrict__ Vh,
                                               void* __restrict__ Y,
                                               const int* __restrict__ flag) {
  __shared__ bf16_t Ksm[FBN * KPITCH];
  __shared__ bf16_t Vtsm[HS * VPITCH];
  __shared__ bf16_t Psm[4][16 * PPITCH];
  const int tid = threadIdx.x;
  const int lane = tid & 63, wave = tid >> 6;
  const int l16 = lane & 15, quad = lane >> 4;
  const int h = blockIdx.y;
  const int qtile = blockIdx.x;
  const int qb = qtile * FBM;
  const int f32out = *flag;

  bf16x8 aq[6];
  const bf16_t* qbase = Qp + ((size_t)h * T_DIM + qb + wave * 16 + l16) * QKD;
#pragma unroll
  for (int c = 0; c < 6; ++c) aq[c] = *(const bf16x8*)(qbase + c * 32 + quad * 8);

  f32x4 o[8] = {};
  float m_i[4], l_i[4];
#pragma unroll
  for (int r = 0; r < 4; ++r) { m_i[r] = -3.0e38f; l_i[r] = 0.f; }

  for (int kt = 0; kt <= qtile; ++kt) {
    __syncthreads();
    {
      const bf16_t* kg = Kp + ((size_t)h * T_DIM + kt * FBN) * QKD;
#pragma unroll
      for (int i = 0; i < 6; ++i) {
        int idx = i * 256 + tid;  // 64 rows * 24 vec8
        int row = idx / 24, c8 = idx % 24;
        bf16x8 v = *(const bf16x8*)(kg + (size_t)row * QKD + c8 * 8);
        *(bf16x8*)(Ksm + row * KPITCH + c8 * 8) = v;
      }
      const bf16_t* vg = Vh + (size_t)(kt * FBN) * C_DIM + h * HS;
#pragma unroll
      for (int i = 0; i < 4; ++i) {
        int idx = i * 256 + tid;  // 64 rows * 16 vec8
        int row = idx / 16, c8 = idx % 16;
        bf16x8 v = *(const bf16x8*)(vg + (size_t)row * C_DIM + c8 * 8);
#pragma unroll
        for (int j = 0; j < 8; ++j) Vtsm[(c8 * 8 + j) * VPITCH + row] = v[j];
      }
    }
    __syncthreads();
    f32x4 sc[4] = {};
#pragma unroll
    for (int nt = 0; nt < 4; ++nt)
#pragma unroll
      for (int c = 0; c < 6; ++c) {
        bf16x8 bk = *(const bf16x8*)(Ksm + (nt * 16 + l16) * KPITCH + c * 32 + quad * 8);
        sc[nt] = __builtin_amdgcn_mfma_f32_16x16x32_bf16(aq[c], bk, sc[nt], 0, 0, 0);
      }
    if (kt == qtile) {
#pragma unroll
      for (int nt = 0; nt < 4; ++nt) {
        int s_loc = nt * 16 + l16;
#pragma unroll
        for (int r = 0; r < 4; ++r) {
          int t_loc = wave * 16 + quad * 4 + r;
          if (s_loc > t_loc) sc[nt][r] = -3.0e38f;
        }
      }
    }
    float p[4][4];
#pragma unroll
    for (int r = 0; r < 4; ++r) {
      float mx = fmaxf(fmaxf(sc[0][r], sc[1][r]), fmaxf(sc[2][r], sc[3][r]));
#pragma unroll
      for (int m = 1; m < 16; m <<= 1) mx = fmaxf(mx, __shfl_xor(mx, m, 64));
      float mn = fmaxf(m_i[r], mx);
      float alpha = exp2f((m_i[r] - mn) * 1.4426950408889634f);
      float rs = 0.f;
#pragma unroll
      for (int nt = 0; nt < 4; ++nt) {
        float pv = exp2f((sc[nt][r] - mn) * 1.4426950408889634f);
        p[nt][r] = pv;
        rs += pv;
      }
#pragma unroll
      for (int m = 1; m < 16; m <<= 1) rs += __shfl_xor(rs, m, 64);
      l_i[r] = l_i[r] * alpha + rs;
      m_i[r] = mn;
#pragma unroll
      for (int dt = 0; dt < 8; ++dt) o[dt][r] *= alpha;
    }
#pragma unroll
    for (int nt = 0; nt < 4; ++nt)
#pragma unroll
      for (int r = 0; r < 4; ++r)
        Psm[wave][(quad * 4 + r) * PPITCH + nt * 16 + l16] = (bf16_t)p[nt][r];
#pragma unroll
    for (int s2 = 0; s2 < 2; ++s2) {
      bf16x8 ap = *(const bf16x8*)(&Psm[wave][l16 * PPITCH + s2 * 32 + quad * 8]);
#pragma unroll
      for (int dt = 0; dt < 8; ++dt) {
        bf16x8 bv = *(const bf16x8*)(Vtsm + (dt * 16 + l16) * VPITCH + s2 * 32 + quad * 8);
        o[dt] = __builtin_amdgcn_mfma_f32_16x16x32_bf16(ap, bv, o[dt], 0, 0, 0);
      }
    }
  }
#pragma unroll
  for (int r = 0; r < 4; ++r) {
    float inv = 1.0f / l_i[r];
    int t = qb + wave * 16 + quad * 4 + r;
#pragma unroll
    for (int dt = 0; dt < 8; ++dt) {
      size_t oi = (size_t)t * C_DIM + h * HS + dt * 16 + l16;
      float val = o[dt][r] * inv;
      if (f32out) ((float*)Y)[oi] = val;
      else        ((bf16_t*)Y)[oi] = (bf16_t)val;
    }
  }
}

// ---------------------------------------------------------------- launch
extern "C" void kernel_launch(void* const* d_in, const int* in_sizes, int n_in,
                              void* d_out, int out_size, void* d_ws, size_t ws_size,
                              hipStream_t stream) {
  bf16_t* w = (bf16_t*)d_ws;
  int* flag = (int*)d_ws;  // first 4 bytes; buffers start at element 64

  // required: 43,909,184 elements * 2B + header
  if (ws_size < (size_t)43909184 * 2 + 128) return;

  // converted-input layout (elements)
  bf16_t* xc   = w + 64;
  bf16_t* dqc  = w + 4194368;
  bf16_t* uqc  = w + 7340096;
  bf16_t* woc  = w + 10485824;
  bf16_t* fcc  = w + 14680128;
  bf16_t* fsc  = w + 14745664;
  bf16_t* dkvc = w + 14811200;
  bf16_t* ukc  = w + 15859776;
  bf16_t* uvc  = w + 16908352;
  bf16_t* qrc  = w + 17956928;
  bf16_t* krc  = w + 19529792;
  // pipeline buffers
  bf16_t* c_q    = w + 19660864;  // 3145728
  bf16_t* W_uq_t = w + 22806592;  // 3145728
  bf16_t* q_up   = w + 25952320;  // 4194304
  bf16_t* q_r    = w + 30146624;  // 2097152
  bf16_t* c_kv   = w + 32243776;  // 1048576
  bf16_t* k_head = w + 33292352;  // 4194304
  bf16_t* vhat   = w + 37486656;  // 4194304
  bf16_t* W_uv_t = w + 41680960;  // 1048576
  bf16_t* Pt     = w + 42729536;  // 1048576
  bf16_t* k_r    = w + 43778112;  // 131072
  // aliases (lifetime-disjoint)
  bf16_t* Qpack = w + 64;        // over xc/dqc (both dead by then)
  bf16_t* Kpack = w + 25952320;  // over q_up/q_r (dead after pack_q_k)

  detect_k<<<1, 64, 0, stream>>>((const bf16_t*)d_in[0], flag);

  struct { const void* in; bf16_t* out; int n; } cv[11] = {
    {d_in[0],  xc,   T_DIM * C_DIM},
    {d_in[1],  fcc,  T_DIM * 32},
    {d_in[2],  fsc,  T_DIM * 32},
    {d_in[3],  dqc,  NLQ * C_DIM},
    {d_in[4],  uqc,  C_DIM * NLQ},
    {d_in[5],  dkvc, NLKV * C_DIM},
    {d_in[6],  ukc,  C_DIM * NLKV},
    {d_in[7],  uvc,  C_DIM * NLKV},
    {d_in[8],  qrc,  NH * DHR * NLQ},
    {d_in[9],  krc,  DHR * C_DIM},
    {d_in[10], woc,  C_DIM * C_DIM},
  };
  for (int i = 0; i < 11; ++i)
    convert_k<<<(cv[i].n + 255) / 256, 256, 0, stream>>>(cv[i].in, cv[i].out, cv[i].n, flag);

  dim3 tb(32, 8);
  // uqc flat viewed as (1536,2048) -> W_uq_t (2048,1536)
  transpose_k<<<dim3(64, 48), tb, 0, stream>>>(uqc, W_uq_t, 1536, 2048);
  // uvc (2048,512) -> W_uv_t (512,2048)
  transpose_k<<<dim3(16, 64), tb, 0, stream>>>(uvc, W_uv_t, 2048, 512);

  // c_q = x @ W_dq^T          (2048,1536,K=2048)
  gemm_nt<<<dim3(16, 12), 256, 0, stream>>>(xc, dqc, c_q, 2048, 1536, 2048, 2048, 2048, 1536);
  // q_up = c_q @ W_uq_t^T     (2048,2048,K=1536)
  gemm_nt<<<dim3(16, 16), 256, 0, stream>>>(c_q, W_uq_t, q_up, 2048, 2048, 1536, 1536, 1536, 2048);
  // q_r = c_q @ W_qr^T        (2048,1024,K=1536)
  gemm_nt<<<dim3(16, 8), 256, 0, stream>>>(c_q, qrc, q_r, 2048, 1024, 1536, 1536, 1536, 1024);
  // c_kv = x @ W_dkv^T        (2048,512,K=2048)
  gemm_nt<<<dim3(16, 4), 256, 0, stream>>>(xc, dkvc, c_kv, 2048, 512, 2048, 2048, 2048, 512);
  // k_r = x @ W_kr^T          (2048,64,K=2048)
  gemm_nt<<<dim3(16, 1), 256, 0, stream>>>(xc, krc, k_r, 2048, 64, 2048, 2048, 2048, 64);
  // k_head = c_kv @ W_uk^T    (2048,2048,K=512)
  gemm_nt<<<dim3(16, 16), 256, 0, stream>>>(c_kv, ukc, k_head, 2048, 2048, 512, 512, 512, 2048);
  // Pt = W_o @ W_uv_t^T = W_o @ W_uv   (2048,512,K=2048)
  gemm_nt<<<dim3(16, 4), 256, 0, stream>>>(woc, W_uv_t, Pt, 2048, 512, 2048, 2048, 2048, 512);
  // vhat = c_kv @ Pt^T        (2048,2048,K=512)
  gemm_nt<<<dim3(16, 16), 256, 0, stream>>>(c_kv, Pt, vhat, 2048, 2048, 512, 512, 512, 2048);

  int pk = (NH * T_DIM * 96 + 255) / 256;
  pack_q_k<<<pk, 256, 0, stream>>>(q_up, q_r, fcc, fsc, Qpack);
  pack_k_k<<<pk, 256, 0, stream>>>(k_head, k_r, fcc, fsc, Kpack);

  flash_k<<<dim3(T_DIM / FBM, NH), 256, 0, stream>>>(Qpack, Kpack, vhat, d_out, flag);
}